// Round 1
// 779.930 us; speedup vs baseline: 1.0762x; 1.0762x over previous
//
#include <hip/hip_runtime.h>

typedef _Float16 half8 __attribute__((ext_vector_type(8)));
typedef float f32x4 __attribute__((ext_vector_type(4)));

// ---------------- workspace layout (int indices) ----------------
// counts / cursors padded to separate 128B lines to avoid atomic serialization.
#define WS_COUNT(e)  ((e) * 32)          // ints 0,32,64,96
#define WS_AOFF(e)   (128 + (e))         // aligned bucket offsets [5]
#define WS_FILL(e)   (136 + (e))         // aoff[e] + counts[e]
#define WS_CUR(e)    (160 + (e) * 32)    // scatter cursors
#define WS_PERM      512                 // perm[N..N+pad]

// ---------------- pass 1: per-element histogram ----------------
__global__ void k_count(const int* __restrict__ zidx, int N, int* __restrict__ ws) {
  __shared__ int lh[4];
  if (threadIdx.x < 4) lh[threadIdx.x] = 0;
  __syncthreads();
  const int i = blockIdx.x * 256 + threadIdx.x;
  const int z = (i < N) ? zidx[i] : -1;
  const int lane = threadIdx.x & 63;
#pragma unroll
  for (int e = 0; e < 4; ++e) {
    unsigned long long m = __ballot(z == e);
    if (lane == 0 && m) atomicAdd(&lh[e], __popcll(m));
  }
  __syncthreads();
  if (threadIdx.x < 4 && lh[threadIdx.x])
    atomicAdd(&ws[WS_COUNT(threadIdx.x)], lh[threadIdx.x]);
}

// ---------------- pass 2: 256-aligned bucket offsets ----------------
__global__ void k_offsets(int* __restrict__ ws) {
  if (threadIdx.x != 0) return;
  int off = 0;
#pragma unroll
  for (int e = 0; e < 4; ++e) {
    int c = ws[WS_COUNT(e)];
    ws[WS_AOFF(e)] = off;
    ws[WS_FILL(e)] = off + c;
    ws[WS_CUR(e)] = off;
    off += (c + 255) & ~255;            // pad each bucket to a 256-atom block
  }
  ws[WS_AOFF(4)] = off;
}

// ---------------- pass 3: scatter atom ids into buckets ----------------
__global__ void k_scatter(const int* __restrict__ zidx, int N, int* __restrict__ ws) {
  __shared__ int wcnt[4][4];   // [wave][e]
  __shared__ int wbase[4][4];  // [wave][e] absolute position base
  const int tid = threadIdx.x;
  const int lane = tid & 63;
  const int wave = tid >> 6;
  const int i = blockIdx.x * 256 + tid;
  const int z = (i < N) ? zidx[i] : -1;
  const unsigned long long m0 = __ballot(z == 0);
  const unsigned long long m1 = __ballot(z == 1);
  const unsigned long long m2 = __ballot(z == 2);
  const unsigned long long m3 = __ballot(z == 3);
  if (lane == 0) {
    wcnt[wave][0] = __popcll(m0);
    wcnt[wave][1] = __popcll(m1);
    wcnt[wave][2] = __popcll(m2);
    wcnt[wave][3] = __popcll(m3);
  }
  __syncthreads();
  if (tid < 4) {   // one lane per element: block-aggregate, one atomic each
    const int e = tid;
    const int c0 = wcnt[0][e], c1 = wcnt[1][e], c2 = wcnt[2][e], c3 = wcnt[3][e];
    const int base = atomicAdd(&ws[WS_CUR(e)], c0 + c1 + c2 + c3);
    wbase[0][e] = base;
    wbase[1][e] = base + c0;
    wbase[2][e] = base + c0 + c1;
    wbase[3][e] = base + c0 + c1 + c2;
  }
  __syncthreads();
  if (z >= 0) {
    const unsigned long long below = (1ull << lane) - 1ull;
    int r, b;
    if (z == 0)      { r = __popcll(m0 & below); b = wbase[wave][0]; }
    else if (z == 1) { r = __popcll(m1 & below); b = wbase[wave][1]; }
    else if (z == 2) { r = __popcll(m2 & below); b = wbase[wave][2]; }
    else             { r = __popcll(m3 & below); b = wbase[wave][3]; }
    ws[WS_PERM + b + r] = i;
  }
}

// ---------------- main: element-uniform blocks, single-element MLP ----------------
// LDS layout: W1[e] as 1024 16B chunks [kt][nt][lane] -> every ds_read_b128 /
// ds_write_b128 is wave-contiguous (conflict-free). 16 KB LDS/block.
__global__ __launch_bounds__(256, 3)
void elemental_sorted_kernel(const float* __restrict__ x,
                             const int* __restrict__ idx_m,
                             const float* __restrict__ W1,
                             const float* __restrict__ b1,
                             const float* __restrict__ W2,
                             const float* __restrict__ b2,
                             const int* __restrict__ ws,
                             float* __restrict__ y) {
  __shared__ _Float16 w1t[8192];  // 16384 B

  const int bstart = blockIdx.x << 8;
  if (bstart >= ws[WS_AOFF(4)]) return;
  int e = 0;
  if (bstart >= ws[WS_AOFF(1)]) e = 1;
  if (bstart >= ws[WS_AOFF(2)]) e = 2;
  if (bstart >= ws[WS_AOFF(3)]) e = 3;
  const int fillE = ws[WS_FILL(e)];

  // stage W1[e] (f32 [d=128][h=64]) -> LDS f16 chunk layout
  const float* w1e = W1 + (size_t)e * 8192;
  const int tid = threadIdx.x;
#pragma unroll
  for (int t = 0; t < 4; ++t) {
    const int ch = tid + t * 256;            // chunk id 0..1023
    const int kt = ch >> 8;
    const int nt = (ch >> 6) & 3;
    const int l2 = ch & 63;
    const int h = nt * 16 + (l2 & 15);
    const int d0 = kt * 32 + (l2 >> 4) * 8;
    half8 hv;
#pragma unroll
    for (int j = 0; j < 8; ++j)
      hv[j] = (_Float16)w1e[(d0 + j) * 64 + h];
    *(half8*)&w1t[ch * 8] = hv;              // contiguous b128 write per wave
  }
  __syncthreads();

  const int lane = tid & 63;
  const int wave = tid >> 6;
  const int c = lane & 15;
  const int q = lane >> 4;
  const int pos = bstart + wave * 64 + lane;
  const int ap = (pos < fillE) ? ws[WS_PERM + pos] : -1;   // gathered atom id (-1 = pad)
  const int iv = (ap >= 0) ? idx_m[ap] : 0;

  // A fragments: lane holds row m = mt*16 + c (tile position), k = q*8..q*8+7 per kt
  half8 af[4][4];
#pragma unroll
  for (int mt = 0; mt < 4; ++mt) {
    int pa = __shfl(ap, mt * 16 + c);
    const f32x4* rp = (const f32x4*)(x + (long)(pa < 0 ? 0 : pa) * 128);
#pragma unroll
    for (int kt = 0; kt < 4; ++kt) {
      f32x4 u0 = rp[kt * 8 + q * 2];
      f32x4 u1 = rp[kt * 8 + q * 2 + 1];
      half8 a;
      a[0] = (_Float16)u0[0]; a[1] = (_Float16)u0[1];
      a[2] = (_Float16)u0[2]; a[3] = (_Float16)u0[3];
      a[4] = (_Float16)u1[0]; a[5] = (_Float16)u1[1];
      a[6] = (_Float16)u1[2]; a[7] = (_Float16)u1[3];
      af[mt][kt] = a;
    }
  }

  f32x4 acc[4][4];
#pragma unroll
  for (int mt = 0; mt < 4; ++mt)
#pragma unroll
    for (int nt = 0; nt < 4; ++nt)
      acc[mt][nt] = (f32x4){0.f, 0.f, 0.f, 0.f};

#pragma unroll
  for (int kt = 0; kt < 4; ++kt)
#pragma unroll
    for (int nt = 0; nt < 4; ++nt) {
      // conflict-free: 64 lanes read 1024 contiguous bytes
      half8 bf = *(const half8*)&w1t[((kt * 4 + nt) * 64 + lane) * 8];
#pragma unroll
      for (int mt = 0; mt < 4; ++mt)
        acc[mt][nt] = __builtin_amdgcn_mfma_f32_16x16x32_f16(af[mt][kt], bf, acc[mt][nt], 0, 0, 0);
    }

  // epilogue: bias + shifted softplus + layer-2 dot + c-lane reduce + atomic
  float b1v[4], w2v[4];
#pragma unroll
  for (int nt = 0; nt < 4; ++nt) {
    b1v[nt] = b1[e * 64 + nt * 16 + c];
    w2v[nt] = W2[e * 64 + nt * 16 + c];
  }
  const float b2e = b2[e];
#pragma unroll
  for (int mt = 0; mt < 4; ++mt) {
#pragma unroll
    for (int i = 0; i < 4; ++i) {
      float s = 0.0f;
#pragma unroll
      for (int nt = 0; nt < 4; ++nt) {
        float tv = acc[mt][nt][i] + b1v[nt];
        float hsp = __logf(1.0f + __expf(tv)) - 0.69314718056f;  // ssp
        s = fmaf(hsp, w2v[nt], s);
      }
      s += __shfl_xor(s, 1);
      s += __shfl_xor(s, 2);
      s += __shfl_xor(s, 4);
      s += __shfl_xor(s, 8);
      const int mloc = mt * 16 + q * 4 + i;
      const int av = __shfl(ap, mloc);
      const int im = __shfl(iv, mloc);
      if (c == 0 && av >= 0)
        atomicAdd(&y[im], s + b2e);
    }
  }
}

// ---------------- fallback: previous verified all-elements kernel ----------------
#define LDSROW_OLD 136

__global__ __launch_bounds__(256, 2)
void elemental_atomwise_kernel(const float* __restrict__ x,
                               const int* __restrict__ zidx,
                               const int* __restrict__ idx_m,
                               const float* __restrict__ W1,
                               const float* __restrict__ b1,
                               const float* __restrict__ W2,
                               const float* __restrict__ b2,
                               float* __restrict__ y,
                               int N) {
  extern __shared__ _Float16 w1t[];
#pragma unroll
  for (int it = 0; it < 32; ++it) {
    int idx4 = threadIdx.x + it * 256;
    f32x4 v = ((const f32x4*)W1)[idx4];
    int lin = idx4 << 2;
    int d = (lin >> 6) & 127;
    int ee = lin >> 13;
    int h = lin & 63;
    int n = ee * 64 + h;
#pragma unroll
    for (int j = 0; j < 4; ++j)
      w1t[(n + j) * LDSROW_OLD + d] = (_Float16)v[j];
  }
  __syncthreads();

  const int lane = threadIdx.x & 63;
  const int wave = threadIdx.x >> 6;
  const int c = lane & 15;
  const int q = lane >> 4;
  const long tile = (long)blockIdx.x * 4 + wave;
  const long base = tile * 64;
  if (base >= N) return;

  int ameta = (base + lane < N) ? (int)(base + lane) : (N - 1);
  const int zvec = zidx[ameta];
  const int ivec = idx_m[ameta];

  half8 af[4][4];
#pragma unroll
  for (int mt = 0; mt < 4; ++mt) {
    long row = base + mt * 16 + c;
    if (row >= N) row = N - 1;
    const f32x4* rp = (const f32x4*)(x + row * 128);
#pragma unroll
    for (int kt = 0; kt < 4; ++kt) {
      f32x4 u0 = rp[kt * 8 + q * 2];
      f32x4 u1 = rp[kt * 8 + q * 2 + 1];
      half8 a;
      a[0] = (_Float16)u0[0]; a[1] = (_Float16)u0[1];
      a[2] = (_Float16)u0[2]; a[3] = (_Float16)u0[3];
      a[4] = (_Float16)u1[0]; a[5] = (_Float16)u1[1];
      a[6] = (_Float16)u1[2]; a[7] = (_Float16)u1[3];
      af[mt][kt] = a;
    }
  }

#pragma unroll
  for (int e = 0; e < 4; ++e) {
    f32x4 acc[4][4];
#pragma unroll
    for (int mt = 0; mt < 4; ++mt)
#pragma unroll
      for (int nt = 0; nt < 4; ++nt)
        acc[mt][nt] = (f32x4){0.f, 0.f, 0.f, 0.f};

#pragma unroll
    for (int kt = 0; kt < 4; ++kt) {
#pragma unroll
      for (int nt = 0; nt < 4; ++nt) {
        half8 bf = *(const half8*)&w1t[(e * 64 + nt * 16 + c) * LDSROW_OLD + kt * 32 + q * 8];
#pragma unroll
        for (int mt = 0; mt < 4; ++mt)
          acc[mt][nt] = __builtin_amdgcn_mfma_f32_16x16x32_f16(af[mt][kt], bf, acc[mt][nt], 0, 0, 0);
      }
    }

    float b1v[4], w2v[4];
#pragma unroll
    for (int nt = 0; nt < 4; ++nt) {
      b1v[nt] = b1[e * 64 + nt * 16 + c];
      w2v[nt] = W2[e * 64 + nt * 16 + c];
    }
    const float b2e = b2[e];
#pragma unroll
    for (int mt = 0; mt < 4; ++mt) {
#pragma unroll
      for (int i = 0; i < 4; ++i) {
        float s = 0.0f;
#pragma unroll
        for (int nt = 0; nt < 4; ++nt) {
          float tv = acc[mt][nt][i] + b1v[nt];
          float hsp = __logf(1.0f + __expf(tv)) - 0.69314718056f;
          s = fmaf(hsp, w2v[nt], s);
        }
        s += __shfl_xor(s, 1);
        s += __shfl_xor(s, 2);
        s += __shfl_xor(s, 4);
        s += __shfl_xor(s, 8);
        int mloc = mt * 16 + q * 4 + i;
        int zm = __shfl(zvec, mloc);
        int im = __shfl(ivec, mloc);
        if (c == 0 && zm == e && base + mloc < N)
          atomicAdd(&y[im], s + b2e);
      }
    }
  }
}

extern "C" void kernel_launch(void* const* d_in, const int* in_sizes, int n_in,
                              void* d_out, int out_size, void* d_ws, size_t ws_size,
                              hipStream_t stream) {
  const float* x = (const float*)d_in[0];
  const int* zidx = (const int*)d_in[1];
  const int* idx_m = (const int*)d_in[2];
  const float* W1 = (const float*)d_in[3];
  const float* b1 = (const float*)d_in[4];
  const float* W2 = (const float*)d_in[5];
  const float* b2 = (const float*)d_in[6];
  float* y = (float*)d_out;

  const int N = in_sizes[0] / 128;

  hipMemsetAsync(d_out, 0, (size_t)out_size * sizeof(float), stream);

  const size_t ws_need = (size_t)(WS_PERM + N + 1024) * sizeof(int);
  if (ws_size >= ws_need) {
    int* ws = (int*)d_ws;
    hipMemsetAsync(d_ws, 0, 1024, stream);  // zero counts region
    const int nb = (N + 255) / 256;
    k_count<<<nb, 256, 0, stream>>>(zidx, N, ws);
    k_offsets<<<1, 64, 0, stream>>>(ws);
    k_scatter<<<nb, 256, 0, stream>>>(zidx, N, ws);
    const int nb4 = (N + 1020 + 255) / 256;  // padded total <= N + 4*255
    elemental_sorted_kernel<<<nb4, 256, 0, stream>>>(x, idx_m, W1, b1, W2, b2, ws, y);
  } else {
    const int tiles = (N + 63) / 64;
    const int blocks = (tiles + 3) / 4;
    const size_t lds_bytes = 256 * LDSROW_OLD * sizeof(_Float16);
    elemental_atomwise_kernel<<<blocks, 256, lds_bytes, stream>>>(
        x, zidx, idx_m, W1, b1, W2, b2, y, N);
  }
}

// Round 2
// 768.520 us; speedup vs baseline: 1.0922x; 1.0148x over previous
//
#include <hip/hip_runtime.h>

typedef _Float16 half8 __attribute__((ext_vector_type(8)));
typedef float f32x4 __attribute__((ext_vector_type(4)));

// ---------------- workspace layout (int indices) ----------------
#define WS_COUNT(e)  ((e) * 32)          // ints 0,32,64,96
#define WS_AOFF(e)   (128 + (e))         // aligned bucket offsets [5]
#define WS_FILL(e)   (136 + (e))         // aoff[e] + counts[e]
#define WS_CUR(e)    (160 + (e) * 32)    // scatter cursors
#define WS_PERM      512                 // perm[N..N+pad]
// W1h (fp16 chunk layout, 4*1024 chunks * 16B = 64 KB) at int offset
// WS_W1H(N) = (512 + N + 1024 + 3) & ~3   (16B-aligned)

// ---------------- pass 1: histogram + W1 -> fp16 chunk-layout convert ----------------
__global__ void k_count(const int* __restrict__ zidx, int N, int* __restrict__ ws,
                        const float* __restrict__ W1, _Float16* __restrict__ w1h) {
  __shared__ int lh[4];
  if (threadIdx.x < 4) lh[threadIdx.x] = 0;
  __syncthreads();
  const int i = blockIdx.x * 256 + threadIdx.x;
  const int z = (i < N) ? zidx[i] : -1;
  const int lane = threadIdx.x & 63;
#pragma unroll
  for (int e = 0; e < 4; ++e) {
    unsigned long long m = __ballot(z == e);
    if (lane == 0 && m) atomicAdd(&lh[e], __popcll(m));
  }
  // first 16 blocks also convert W1 (f32 [e][d=128][h=64]) into the chunked
  // fp16 layout the main kernel stages from: chunk ch of element e holds
  // halfs [j=0..7] = W1[e][d0+j][h], h = nt*16+(l2&15), d0 = kt*32+(l2>>4)*8
  if (blockIdx.x < 16) {
    const int cg = blockIdx.x * 256 + threadIdx.x;   // 0..4095
    const int e = cg >> 10, ch = cg & 1023;
    const int kt = ch >> 8, nt = (ch >> 6) & 3, l2 = ch & 63;
    const int h = nt * 16 + (l2 & 15);
    const int d0 = kt * 32 + (l2 >> 4) * 8;
    const float* w1e = W1 + (size_t)e * 8192;
    half8 hv;
#pragma unroll
    for (int j = 0; j < 8; ++j) hv[j] = (_Float16)w1e[(d0 + j) * 64 + h];
    *(half8*)&w1h[(size_t)cg * 8] = hv;
  }
  __syncthreads();
  if (threadIdx.x < 4 && lh[threadIdx.x])
    atomicAdd(&ws[WS_COUNT(threadIdx.x)], lh[threadIdx.x]);
}

// ---------------- pass 2: 256-aligned bucket offsets ----------------
__global__ void k_offsets(int* __restrict__ ws) {
  if (threadIdx.x != 0) return;
  int off = 0;
#pragma unroll
  for (int e = 0; e < 4; ++e) {
    int c = ws[WS_COUNT(e)];
    ws[WS_AOFF(e)] = off;
    ws[WS_FILL(e)] = off + c;
    ws[WS_CUR(e)] = off;
    off += (c + 255) & ~255;
  }
  ws[WS_AOFF(4)] = off;
}

// ---------------- pass 3: scatter atom ids into buckets ----------------
__global__ void k_scatter(const int* __restrict__ zidx, int N, int* __restrict__ ws) {
  __shared__ int wcnt[4][4];
  __shared__ int wbase[4][4];
  const int tid = threadIdx.x;
  const int lane = tid & 63;
  const int wave = tid >> 6;
  const int i = blockIdx.x * 256 + tid;
  const int z = (i < N) ? zidx[i] : -1;
  const unsigned long long m0 = __ballot(z == 0);
  const unsigned long long m1 = __ballot(z == 1);
  const unsigned long long m2 = __ballot(z == 2);
  const unsigned long long m3 = __ballot(z == 3);
  if (lane == 0) {
    wcnt[wave][0] = __popcll(m0);
    wcnt[wave][1] = __popcll(m1);
    wcnt[wave][2] = __popcll(m2);
    wcnt[wave][3] = __popcll(m3);
  }
  __syncthreads();
  if (tid < 4) {
    const int e = tid;
    const int c0 = wcnt[0][e], c1 = wcnt[1][e], c2 = wcnt[2][e], c3 = wcnt[3][e];
    const int base = atomicAdd(&ws[WS_CUR(e)], c0 + c1 + c2 + c3);
    wbase[0][e] = base;
    wbase[1][e] = base + c0;
    wbase[2][e] = base + c0 + c1;
    wbase[3][e] = base + c0 + c1 + c2;
  }
  __syncthreads();
  if (z >= 0) {
    const unsigned long long below = (1ull << lane) - 1ull;
    int r, b;
    if (z == 0)      { r = __popcll(m0 & below); b = wbase[wave][0]; }
    else if (z == 1) { r = __popcll(m1 & below); b = wbase[wave][1]; }
    else if (z == 2) { r = __popcll(m2 & below); b = wbase[wave][2]; }
    else             { r = __popcll(m3 & below); b = wbase[wave][3]; }
    ws[WS_PERM + b + r] = i;
  }
}

// ---------------- main: 16 atoms/wave, 64 atoms/block, zero-spill ----------------
__global__ __launch_bounds__(256, 4)
void elemental_sorted16(const float* __restrict__ x,
                        const int* __restrict__ idx_m,
                        const _Float16* __restrict__ w1h,
                        const float* __restrict__ b1,
                        const float* __restrict__ W2,
                        const float* __restrict__ b2,
                        const int* __restrict__ ws,
                        float* __restrict__ y) {
  __shared__ _Float16 w1t[8192];  // 16 KB

  const int bstart = blockIdx.x * 64;
  if (bstart >= ws[WS_AOFF(4)]) return;
  int e = 0;
  if (bstart >= ws[WS_AOFF(1)]) e = 1;
  if (bstart >= ws[WS_AOFF(2)]) e = 2;
  if (bstart >= ws[WS_AOFF(3)]) e = 3;
  const int fillE = ws[WS_FILL(e)];

  // stage W1h[e] -> LDS: 4 coalesced half8 copies per thread
  const int tid = threadIdx.x;
  const half8* src = (const half8*)w1h + (size_t)e * 1024;
#pragma unroll
  for (int it = 0; it < 4; ++it) {
    const int kk = it * 256 + tid;
    *(half8*)&w1t[kk * 8] = src[kk];
  }
  __syncthreads();

  const int lane = tid & 63;
  const int wave = tid >> 6;
  const int c = lane & 15;
  const int q = lane >> 4;
  const int pos = bstart + wave * 16 + c;          // lane owns atom slot c
  const int ap = (pos < fillE) ? ws[WS_PERM + pos] : -1;
  const int iv = (ap >= 0) ? idx_m[ap] : 0;

  // A frags: lane's row = ap, k = kt*32 + q*8 .. +7 (4 q-lanes share a row)
  const f32x4* rp = (const f32x4*)(x + (long)(ap < 0 ? 0 : ap) * 128);
  half8 af[4];
#pragma unroll
  for (int kt = 0; kt < 4; ++kt) {
    f32x4 u0 = rp[kt * 8 + q * 2];
    f32x4 u1 = rp[kt * 8 + q * 2 + 1];
    half8 a;
    a[0] = (_Float16)u0[0]; a[1] = (_Float16)u0[1];
    a[2] = (_Float16)u0[2]; a[3] = (_Float16)u0[3];
    a[4] = (_Float16)u1[0]; a[5] = (_Float16)u1[1];
    a[6] = (_Float16)u1[2]; a[7] = (_Float16)u1[3];
    af[kt] = a;
  }

  f32x4 acc[4];
#pragma unroll
  for (int nt = 0; nt < 4; ++nt) acc[nt] = (f32x4){0.f, 0.f, 0.f, 0.f};
#pragma unroll
  for (int kt = 0; kt < 4; ++kt)
#pragma unroll
    for (int nt = 0; nt < 4; ++nt) {
      // conflict-free: 64 lanes read 1024 contiguous LDS bytes
      half8 bf = *(const half8*)&w1t[((kt * 4 + nt) * 64 + lane) * 8];
      acc[nt] = __builtin_amdgcn_mfma_f32_16x16x32_f16(af[kt], bf, acc[nt], 0, 0, 0);
    }

  // epilogue: bias + ssp + layer-2 dot + 16-lane reduce + atomic
  float b1v[4], w2v[4];
#pragma unroll
  for (int nt = 0; nt < 4; ++nt) {
    b1v[nt] = b1[e * 64 + nt * 16 + c];
    w2v[nt] = W2[e * 64 + nt * 16 + c];
  }
  const float b2e = b2[e];
#pragma unroll
  for (int i = 0; i < 4; ++i) {
    float s = 0.0f;
#pragma unroll
    for (int nt = 0; nt < 4; ++nt) {
      float tv = acc[nt][i] + b1v[nt];
      float hsp = __logf(1.0f + __expf(tv)) - 0.69314718056f;  // ssp
      s = fmaf(hsp, w2v[nt], s);
    }
    s += __shfl_xor(s, 1);
    s += __shfl_xor(s, 2);
    s += __shfl_xor(s, 4);
    s += __shfl_xor(s, 8);
    const int slot = q * 4 + i;                 // C layout: row = q*4+i, col = c
    const int av = __shfl(ap, slot);
    const int im = __shfl(iv, slot);
    if (c == 0 && av >= 0)
      atomicAdd(&y[im], s + b2e);
  }
}

// ---------------- fallback: verified all-elements kernel ----------------
#define LDSROW_OLD 136

__global__ __launch_bounds__(256, 2)
void elemental_atomwise_kernel(const float* __restrict__ x,
                               const int* __restrict__ zidx,
                               const int* __restrict__ idx_m,
                               const float* __restrict__ W1,
                               const float* __restrict__ b1,
                               const float* __restrict__ W2,
                               const float* __restrict__ b2,
                               float* __restrict__ y,
                               int N) {
  extern __shared__ _Float16 w1t[];
#pragma unroll
  for (int it = 0; it < 32; ++it) {
    int idx4 = threadIdx.x + it * 256;
    f32x4 v = ((const f32x4*)W1)[idx4];
    int lin = idx4 << 2;
    int d = (lin >> 6) & 127;
    int ee = lin >> 13;
    int h = lin & 63;
    int n = ee * 64 + h;
#pragma unroll
    for (int j = 0; j < 4; ++j)
      w1t[(n + j) * LDSROW_OLD + d] = (_Float16)v[j];
  }
  __syncthreads();

  const int lane = threadIdx.x & 63;
  const int wave = threadIdx.x >> 6;
  const int c = lane & 15;
  const int q = lane >> 4;
  const long tile = (long)blockIdx.x * 4 + wave;
  const long base = tile * 64;
  if (base >= N) return;

  int ameta = (base + lane < N) ? (int)(base + lane) : (N - 1);
  const int zvec = zidx[ameta];
  const int ivec = idx_m[ameta];

  half8 af[4][4];
#pragma unroll
  for (int mt = 0; mt < 4; ++mt) {
    long row = base + mt * 16 + c;
    if (row >= N) row = N - 1;
    const f32x4* rp = (const f32x4*)(x + row * 128);
#pragma unroll
    for (int kt = 0; kt < 4; ++kt) {
      f32x4 u0 = rp[kt * 8 + q * 2];
      f32x4 u1 = rp[kt * 8 + q * 2 + 1];
      half8 a;
      a[0] = (_Float16)u0[0]; a[1] = (_Float16)u0[1];
      a[2] = (_Float16)u0[2]; a[3] = (_Float16)u0[3];
      a[4] = (_Float16)u1[0]; a[5] = (_Float16)u1[1];
      a[6] = (_Float16)u1[2]; a[7] = (_Float16)u1[3];
      af[mt][kt] = a;
    }
  }

#pragma unroll
  for (int e = 0; e < 4; ++e) {
    f32x4 acc[4][4];
#pragma unroll
    for (int mt = 0; mt < 4; ++mt)
#pragma unroll
      for (int nt = 0; nt < 4; ++nt)
        acc[mt][nt] = (f32x4){0.f, 0.f, 0.f, 0.f};

#pragma unroll
    for (int kt = 0; kt < 4; ++kt) {
#pragma unroll
      for (int nt = 0; nt < 4; ++nt) {
        half8 bf = *(const half8*)&w1t[(e * 64 + nt * 16 + c) * LDSROW_OLD + kt * 32 + q * 8];
#pragma unroll
        for (int mt = 0; mt < 4; ++mt)
          acc[mt][nt] = __builtin_amdgcn_mfma_f32_16x16x32_f16(af[mt][kt], bf, acc[mt][nt], 0, 0, 0);
      }
    }

    float b1v[4], w2v[4];
#pragma unroll
    for (int nt = 0; nt < 4; ++nt) {
      b1v[nt] = b1[e * 64 + nt * 16 + c];
      w2v[nt] = W2[e * 64 + nt * 16 + c];
    }
    const float b2e = b2[e];
#pragma unroll
    for (int mt = 0; mt < 4; ++mt) {
#pragma unroll
      for (int i = 0; i < 4; ++i) {
        float s = 0.0f;
#pragma unroll
        for (int nt = 0; nt < 4; ++nt) {
          float tv = acc[mt][nt][i] + b1v[nt];
          float hsp = __logf(1.0f + __expf(tv)) - 0.69314718056f;
          s = fmaf(hsp, w2v[nt], s);
        }
        s += __shfl_xor(s, 1);
        s += __shfl_xor(s, 2);
        s += __shfl_xor(s, 4);
        s += __shfl_xor(s, 8);
        int mloc = mt * 16 + q * 4 + i;
        int zm = __shfl(zvec, mloc);
        int im = __shfl(ivec, mloc);
        if (c == 0 && zm == e && base + mloc < N)
          atomicAdd(&y[im], s + b2e);
      }
    }
  }
}

extern "C" void kernel_launch(void* const* d_in, const int* in_sizes, int n_in,
                              void* d_out, int out_size, void* d_ws, size_t ws_size,
                              hipStream_t stream) {
  const float* x = (const float*)d_in[0];
  const int* zidx = (const int*)d_in[1];
  const int* idx_m = (const int*)d_in[2];
  const float* W1 = (const float*)d_in[3];
  const float* b1 = (const float*)d_in[4];
  const float* W2 = (const float*)d_in[5];
  const float* b2 = (const float*)d_in[6];
  float* y = (float*)d_out;

  const int N = in_sizes[0] / 128;

  hipMemsetAsync(d_out, 0, (size_t)out_size * sizeof(float), stream);

  const int w1h_off = (512 + N + 1024 + 3) & ~3;          // int offset, 16B-aligned
  const size_t ws_need = (size_t)w1h_off * sizeof(int) + 65536;
  if (ws_size >= ws_need) {
    int* ws = (int*)d_ws;
    _Float16* w1h = (_Float16*)(ws + w1h_off);
    hipMemsetAsync(d_ws, 0, 1024, stream);                // zero counts region
    const int nb = (N + 255) / 256;
    const int nbc = nb < 16 ? 16 : nb;
    k_count<<<nbc, 256, 0, stream>>>(zidx, N, ws, W1, w1h);
    k_offsets<<<1, 64, 0, stream>>>(ws);
    k_scatter<<<nb, 256, 0, stream>>>(zidx, N, ws);
    const int nb64 = (N + 1020 + 63) / 64;                // padded total <= N + 4*255
    elemental_sorted16<<<nb64, 256, 0, stream>>>(x, idx_m, w1h, b1, W2, b2, ws, y);
  } else {
    const int tiles = (N + 63) / 64;
    const int blocks = (tiles + 3) / 4;
    const size_t lds_bytes = 256 * LDSROW_OLD * sizeof(_Float16);
    elemental_atomwise_kernel<<<blocks, 256, lds_bytes, stream>>>(
        x, zidx, idx_m, W1, b1, W2, b2, y, N);
  }
}

// Round 3
// 703.870 us; speedup vs baseline: 1.1925x; 1.0918x over previous
//
#include <hip/hip_runtime.h>

typedef _Float16 half8 __attribute__((ext_vector_type(8)));
typedef float f32x4 __attribute__((ext_vector_type(4)));

// ---------------- workspace layout (int indices) ----------------
#define WS_COUNT(e)  ((e) * 32)          // ints 0,32,64,96
#define WS_CUR(e)    (160 + (e) * 32)    // zero-based scatter cursors (160..256)
#define WS_PERM      512                 // perm[N + 4*512 pad]
// W1h (fp16 chunk layout, 4*1024 chunks * 16B = 64 KB) after perm, 16B-aligned

// ---------------- pass 1: histogram (1024 atoms/block) + W1 fp16 convert ----------------
__global__ void k_count(const int* __restrict__ zidx, int N, int* __restrict__ ws,
                        const float* __restrict__ W1, _Float16* __restrict__ w1h) {
  __shared__ int lh[4];
  if (threadIdx.x < 4) lh[threadIdx.x] = 0;
  // first 16 blocks also convert W1 (f32 [e][d=128][h=64]) into chunked fp16:
  // chunk cg: halfs[j] = W1[e][d0+j][h], h = nt*16+(l2&15), d0 = kt*32+(l2>>4)*8
  if (blockIdx.x < 16) {
    const int cg = blockIdx.x * 256 + threadIdx.x;   // 0..4095
    const int e = cg >> 10, ch = cg & 1023;
    const int kt = ch >> 8, nt = (ch >> 6) & 3, l2 = ch & 63;
    const int h = nt * 16 + (l2 & 15);
    const int d0 = kt * 32 + (l2 >> 4) * 8;
    const float* w1e = W1 + (size_t)e * 8192;
    half8 hv;
#pragma unroll
    for (int j = 0; j < 8; ++j) hv[j] = (_Float16)w1e[(d0 + j) * 64 + h];
    *(half8*)&w1h[(size_t)cg * 8] = hv;
  }
  __syncthreads();
  const int lane = threadIdx.x & 63;
  const int base = blockIdx.x * 1024;
  int pc[4] = {0, 0, 0, 0};
#pragma unroll
  for (int it = 0; it < 4; ++it) {
    const int i = base + it * 256 + threadIdx.x;
    const int z = (i < N) ? zidx[i] : -1;
#pragma unroll
    for (int e = 0; e < 4; ++e) {
      unsigned long long m = __ballot(z == e);
      if (lane == 0) pc[e] += __popcll(m);
    }
  }
  if (lane == 0) {
#pragma unroll
    for (int e = 0; e < 4; ++e)
      if (pc[e]) atomicAdd(&lh[e], pc[e]);
  }
  __syncthreads();
  if (threadIdx.x < 4 && lh[threadIdx.x])
    atomicAdd(&ws[WS_COUNT(threadIdx.x)], lh[threadIdx.x]);
}

// ---------------- pass 2: scatter (1024 atoms/block, 1 atomic per e per block) ----------------
__global__ void k_scatter(const int* __restrict__ zidx, int N, int* __restrict__ ws) {
  __shared__ int cnts[4][4][4];  // [iter][wave][e]
  __shared__ int pb[4][4][4];    // absolute write base per (iter,wave,e)
  const int tid = threadIdx.x, lane = tid & 63, wave = tid >> 6;
  const int base = blockIdx.x * 1024;
  int zz[4];
#pragma unroll
  for (int it = 0; it < 4; ++it) {
    const int i = base + it * 256 + tid;
    zz[it] = (i < N) ? zidx[i] : -1;
#pragma unroll
    for (int e = 0; e < 4; ++e) {
      unsigned long long m = __ballot(zz[it] == e);
      if (lane == 0) cnts[it][wave][e] = __popcll(m);
    }
  }
  __syncthreads();
  if (tid < 4) {
    const int e = tid;
    int off = 0, aoffe = 0;
#pragma unroll
    for (int k = 0; k < 4; ++k) {
      int ck = ws[WS_COUNT(k)];
      if (k == e) aoffe = off;
      off += (ck + 511) & ~511;
    }
    int tot = 0;
#pragma unroll
    for (int it = 0; it < 4; ++it)
#pragma unroll
      for (int w = 0; w < 4; ++w) tot += cnts[it][w][e];
    const int cur = atomicAdd(&ws[WS_CUR(e)], tot);
    int run = aoffe + cur;
#pragma unroll
    for (int it = 0; it < 4; ++it)
#pragma unroll
      for (int w = 0; w < 4; ++w) { pb[it][w][e] = run; run += cnts[it][w][e]; }
  }
  __syncthreads();
  const unsigned long long below = (1ull << lane) - 1ull;
#pragma unroll
  for (int it = 0; it < 4; ++it) {
    const int z = zz[it];
    const unsigned long long m0 = __ballot(z == 0);
    const unsigned long long m1 = __ballot(z == 1);
    const unsigned long long m2 = __ballot(z == 2);
    const unsigned long long m3 = __ballot(z == 3);
    if (z >= 0) {
      const unsigned long long me = (z == 0) ? m0 : (z == 1) ? m1 : (z == 2) ? m2 : m3;
      const int r = __popcll(me & below);
      ws[WS_PERM + pb[it][wave][z] + r] = base + it * 256 + tid;
    }
  }
}

// ---------------- main: 512 atoms/block (8 groups), pipelined, seg-scan atomics ----------------
#define LOADF(dst, g_) do {                                                     \
    const int ap_ = apv[g_];                                                    \
    const f32x4* rp_ = (const f32x4*)(x + (long)(ap_ < 0 ? 0 : ap_) * 128);     \
    _Pragma("unroll")                                                           \
    for (int kt = 0; kt < 4; ++kt) {                                            \
      f32x4 u0 = rp_[kt * 8 + q * 2];                                           \
      f32x4 u1 = rp_[kt * 8 + q * 2 + 1];                                       \
      half8 a;                                                                  \
      a[0] = (_Float16)u0[0]; a[1] = (_Float16)u0[1];                           \
      a[2] = (_Float16)u0[2]; a[3] = (_Float16)u0[3];                           \
      a[4] = (_Float16)u1[0]; a[5] = (_Float16)u1[1];                           \
      a[6] = (_Float16)u1[2]; a[7] = (_Float16)u1[3];                           \
      dst[kt] = a;                                                              \
    }                                                                           \
  } while (0)

#define COMPUTE(g_, af_) do {                                                   \
    f32x4 acc[4];                                                               \
    _Pragma("unroll")                                                           \
    for (int nt = 0; nt < 4; ++nt) acc[nt] = (f32x4){0.f, 0.f, 0.f, 0.f};       \
    _Pragma("unroll")                                                           \
    for (int kt = 0; kt < 4; ++kt)                                              \
      _Pragma("unroll")                                                         \
      for (int nt = 0; nt < 4; ++nt) {                                          \
        half8 bf = *(const half8*)&w1t[((kt * 4 + nt) * 64 + lane) * 8];        \
        acc[nt] = __builtin_amdgcn_mfma_f32_16x16x32_f16(af_[kt], bf, acc[nt], 0, 0, 0); \
      }                                                                         \
    float sv[4];                                                                \
    _Pragma("unroll")                                                           \
    for (int i = 0; i < 4; ++i) {                                               \
      float s = 0.0f;                                                           \
      _Pragma("unroll")                                                         \
      for (int nt = 0; nt < 4; ++nt) {                                          \
        float tv = acc[nt][i] + b1v[nt];                                        \
        float hsp = __logf(1.0f + __expf(tv)) - 0.69314718056f;                 \
        s = fmaf(hsp, w2v[nt], s);                                              \
      }                                                                         \
      s += __shfl_xor(s, 1);                                                    \
      s += __shfl_xor(s, 2);                                                    \
      s += __shfl_xor(s, 4);                                                    \
      s += __shfl_xor(s, 8);                                                    \
      sv[i] = s;                                                                \
    }                                                                           \
    /* transpose: lane l<16 gets slot l's sum (slot l = (l>>2)*4 + (l&3)) */    \
    const int srcl = (lane >> 2) << 4;                                          \
    float t0 = __shfl(sv[0], srcl);                                             \
    float t1 = __shfl(sv[1], srcl);                                             \
    float t2 = __shfl(sv[2], srcl);                                             \
    float t3 = __shfl(sv[3], srcl);                                             \
    const int r3 = lane & 3;                                                    \
    float val = (r3 == 0) ? t0 : (r3 == 1) ? t1 : (r3 == 2) ? t2 : t3;          \
    const int apl = apv[g_];                                                    \
    const int ivl = ivv[g_];                                                    \
    val = (apl >= 0) ? val + b2e : 0.0f;                                        \
    const int ivp = __shfl_up(ivl, 1);                                          \
    const int head = (lane == 0) || (ivl != ivp);                               \
    int flg = head;                                                             \
    float v = val;                                                              \
    _Pragma("unroll")                                                           \
    for (int d = 1; d < 16; d <<= 1) {                                          \
      float v2 = __shfl_up(v, d);                                               \
      int f2 = __shfl_up(flg, d);                                               \
      if (lane >= d && !flg) v += v2;                                           \
      if (lane >= d) flg |= f2;                                                 \
    }                                                                           \
    const int nh = __shfl_down(head, 1);                                        \
    if (lane < 16 && ((lane == 15) || nh)) atomicAdd(&y[ivl], v);               \
  } while (0)

__global__ __launch_bounds__(256, 4)
void elemental_main(const float* __restrict__ x,
                    const int* __restrict__ idx_m,
                    const _Float16* __restrict__ w1h,
                    const float* __restrict__ b1,
                    const float* __restrict__ W2,
                    const float* __restrict__ b2,
                    const int* __restrict__ ws,
                    float* __restrict__ y) {
  __shared__ _Float16 w1t[8192];  // 16 KB

  int cw[4];
#pragma unroll
  for (int k = 0; k < 4; ++k) cw[k] = ws[WS_COUNT(k)];
  const int aoff1 = (cw[0] + 511) & ~511;
  const int aoff2 = aoff1 + ((cw[1] + 511) & ~511);
  const int aoff3 = aoff2 + ((cw[2] + 511) & ~511);
  const int aoff4 = aoff3 + ((cw[3] + 511) & ~511);
  const int bstart = blockIdx.x * 512;
  if (bstart >= aoff4) return;
  int e = 0, ao = 0;
  if (bstart >= aoff1) { e = 1; ao = aoff1; }
  if (bstart >= aoff2) { e = 2; ao = aoff2; }
  if (bstart >= aoff3) { e = 3; ao = aoff3; }
  const int fillE = ao + cw[e];

  // stage W1h[e] -> LDS (coalesced b128)
  const int tid = threadIdx.x;
  const half8* src = (const half8*)w1h + (size_t)e * 1024;
#pragma unroll
  for (int it = 0; it < 4; ++it) {
    const int kk = it * 256 + tid;
    *(half8*)&w1t[kk * 8] = src[kk];
  }

  const int lane = tid & 63;
  const int wave = tid >> 6;
  const int c = lane & 15;
  const int q = lane >> 4;

  // hoisted per-element epilogue constants
  float b1v[4], w2v[4];
#pragma unroll
  for (int nt = 0; nt < 4; ++nt) {
    b1v[nt] = b1[e * 64 + nt * 16 + c];
    w2v[nt] = W2[e * 64 + nt * 16 + c];
  }
  const float b2e = b2[e];

  // batch all 8 groups' perm + idx_m loads up front
  int apv[8], ivv[8];
  const int pbase = bstart + wave * 16 + c;
#pragma unroll
  for (int g = 0; g < 8; ++g) {
    const int pos = pbase + g * 64;
    apv[g] = (pos < fillE) ? ws[WS_PERM + pos] : -1;
  }
#pragma unroll
  for (int g = 0; g < 8; ++g)
    ivv[g] = (apv[g] >= 0) ? idx_m[apv[g]] : 0;

  __syncthreads();

  // 2-deep register double-buffer pipeline over 8 groups
  half8 afA[4], afB[4];
  LOADF(afA, 0);
  LOADF(afB, 1);
  COMPUTE(0, afA);
  LOADF(afA, 2);
  COMPUTE(1, afB);
  LOADF(afB, 3);
  COMPUTE(2, afA);
  LOADF(afA, 4);
  COMPUTE(3, afB);
  LOADF(afB, 5);
  COMPUTE(4, afA);
  LOADF(afA, 6);
  COMPUTE(5, afB);
  LOADF(afB, 7);
  COMPUTE(6, afA);
  COMPUTE(7, afB);
}

// ---------------- fallback: verified all-elements kernel ----------------
#define LDSROW_OLD 136

__global__ __launch_bounds__(256, 2)
void elemental_atomwise_kernel(const float* __restrict__ x,
                               const int* __restrict__ zidx,
                               const int* __restrict__ idx_m,
                               const float* __restrict__ W1,
                               const float* __restrict__ b1,
                               const float* __restrict__ W2,
                               const float* __restrict__ b2,
                               float* __restrict__ y,
                               int N) {
  extern __shared__ _Float16 w1t[];
#pragma unroll
  for (int it = 0; it < 32; ++it) {
    int idx4 = threadIdx.x + it * 256;
    f32x4 v = ((const f32x4*)W1)[idx4];
    int lin = idx4 << 2;
    int d = (lin >> 6) & 127;
    int ee = lin >> 13;
    int h = lin & 63;
    int n = ee * 64 + h;
#pragma unroll
    for (int j = 0; j < 4; ++j)
      w1t[(n + j) * LDSROW_OLD + d] = (_Float16)v[j];
  }
  __syncthreads();

  const int lane = threadIdx.x & 63;
  const int wave = threadIdx.x >> 6;
  const int c = lane & 15;
  const int q = lane >> 4;
  const long tile = (long)blockIdx.x * 4 + wave;
  const long base = tile * 64;
  if (base >= N) return;

  int ameta = (base + lane < N) ? (int)(base + lane) : (N - 1);
  const int zvec = zidx[ameta];
  const int ivec = idx_m[ameta];

  half8 af[4][4];
#pragma unroll
  for (int mt = 0; mt < 4; ++mt) {
    long row = base + mt * 16 + c;
    if (row >= N) row = N - 1;
    const f32x4* rp = (const f32x4*)(x + row * 128);
#pragma unroll
    for (int kt = 0; kt < 4; ++kt) {
      f32x4 u0 = rp[kt * 8 + q * 2];
      f32x4 u1 = rp[kt * 8 + q * 2 + 1];
      half8 a;
      a[0] = (_Float16)u0[0]; a[1] = (_Float16)u0[1];
      a[2] = (_Float16)u0[2]; a[3] = (_Float16)u0[3];
      a[4] = (_Float16)u1[0]; a[5] = (_Float16)u1[1];
      a[6] = (_Float16)u1[2]; a[7] = (_Float16)u1[3];
      af[mt][kt] = a;
    }
  }

#pragma unroll
  for (int e = 0; e < 4; ++e) {
    f32x4 acc[4][4];
#pragma unroll
    for (int mt = 0; mt < 4; ++mt)
#pragma unroll
      for (int nt = 0; nt < 4; ++nt)
        acc[mt][nt] = (f32x4){0.f, 0.f, 0.f, 0.f};

#pragma unroll
    for (int kt = 0; kt < 4; ++kt) {
#pragma unroll
      for (int nt = 0; nt < 4; ++nt) {
        half8 bf = *(const half8*)&w1t[(e * 64 + nt * 16 + c) * LDSROW_OLD + kt * 32 + q * 8];
#pragma unroll
        for (int mt = 0; mt < 4; ++mt)
          acc[mt][nt] = __builtin_amdgcn_mfma_f32_16x16x32_f16(af[mt][kt], bf, acc[mt][nt], 0, 0, 0);
      }
    }

    float b1v[4], w2v[4];
#pragma unroll
    for (int nt = 0; nt < 4; ++nt) {
      b1v[nt] = b1[e * 64 + nt * 16 + c];
      w2v[nt] = W2[e * 64 + nt * 16 + c];
    }
    const float b2e = b2[e];
#pragma unroll
    for (int mt = 0; mt < 4; ++mt) {
#pragma unroll
      for (int i = 0; i < 4; ++i) {
        float s = 0.0f;
#pragma unroll
        for (int nt = 0; nt < 4; ++nt) {
          float tv = acc[mt][nt][i] + b1v[nt];
          float hsp = __logf(1.0f + __expf(tv)) - 0.69314718056f;
          s = fmaf(hsp, w2v[nt], s);
        }
        s += __shfl_xor(s, 1);
        s += __shfl_xor(s, 2);
        s += __shfl_xor(s, 4);
        s += __shfl_xor(s, 8);
        int mloc = mt * 16 + q * 4 + i;
        int zm = __shfl(zvec, mloc);
        int im = __shfl(ivec, mloc);
        if (c == 0 && zm == e && base + mloc < N)
          atomicAdd(&y[im], s + b2e);
      }
    }
  }
}

extern "C" void kernel_launch(void* const* d_in, const int* in_sizes, int n_in,
                              void* d_out, int out_size, void* d_ws, size_t ws_size,
                              hipStream_t stream) {
  const float* x = (const float*)d_in[0];
  const int* zidx = (const int*)d_in[1];
  const int* idx_m = (const int*)d_in[2];
  const float* W1 = (const float*)d_in[3];
  const float* b1 = (const float*)d_in[4];
  const float* W2 = (const float*)d_in[5];
  const float* b2 = (const float*)d_in[6];
  float* y = (float*)d_out;

  const int N = in_sizes[0] / 128;

  hipMemsetAsync(d_out, 0, (size_t)out_size * sizeof(float), stream);

  const int w1h_off = (512 + N + 2048 + 3) & ~3;          // int offset, 16B-aligned
  const size_t ws_need = (size_t)w1h_off * sizeof(int) + 65536;
  if (ws_size >= ws_need) {
    int* ws = (int*)d_ws;
    _Float16* w1h = (_Float16*)(ws + w1h_off);
    hipMemsetAsync(d_ws, 0, 2048, stream);                // zero counts + cursors
    const int nb = (N + 1023) / 1024;
    const int nbc = nb < 16 ? 16 : nb;
    k_count<<<nbc, 256, 0, stream>>>(zidx, N, ws, W1, w1h);
    k_scatter<<<nb, 256, 0, stream>>>(zidx, N, ws);
    const int mb = (N + 2555) / 512;                      // covers max padded total
    elemental_main<<<mb, 256, 0, stream>>>(x, idx_m, w1h, b1, W2, b2, ws, y);
  } else {
    const int tiles = (N + 63) / 64;
    const int blocks = (tiles + 3) / 4;
    const size_t lds_bytes = 256 * LDSROW_OLD * sizeof(_Float16);
    elemental_atomwise_kernel<<<blocks, 256, lds_bytes, stream>>>(
        x, zidx, idx_m, W1, b1, W2, b2, y, N);
  }
}